// Round 2
// baseline (144.917 us; speedup 1.0000x reference)
//
#include <hip/hip_runtime.h>

#define MAX_DISP 48

// Geometry fixed by reference: n=2, c=32, h=128, w=256
// out[n][c][d][h][x] = (x>=d) ? l[n][c][h][x] - r[n][c][h][x-d] : 1.0f
// out shape (n, c, MAX_DISP, h, w) float32 = 402.7 MB  -> write-BW bound.

constexpr int W  = 256;
constexpr int H  = 128;
constexpr int D  = MAX_DISP;      // 48
constexpr int NC = 64;            // n*c

// One block per (nc, d) pair. Block writes the 128 KB contiguous slice
// out[nc][d][:][:] as 32 sequential 4 KB chunks (256 threads x float4).
// l/r planes (128 KB each) are read through L2, shared by the 48 blocks
// with the same nc.
__global__ __launch_bounds__(256) void cost_volume_kernel(
    const float* __restrict__ l,
    const float* __restrict__ r,
    float* __restrict__ out)
{
    const int b  = blockIdx.x;        // nc*D + d, in [0, 3072)
    const int d  = b % D;
    const int nc = b / D;

    const float* __restrict__ lp = l + (size_t)nc * H * W;
    const float* __restrict__ rp = r + (size_t)nc * H * W;
    float* __restrict__ op = out + (size_t)b * H * W;   // out[nc][d] slice

    const int t = threadIdx.x;

    #pragma unroll
    for (int k = 0; k < (H * W / 4) / 256; ++k) {       // 32 iterations
        const int flat = (t + k * 256) * 4;             // element index in slice
        const int x    = flat & (W - 1);                // column within row

        const float4 lv = *reinterpret_cast<const float4*>(lp + flat);

        // Shifted r reads: consecutive lanes -> consecutive addresses
        // (coalesced scalar loads). Clamp handles the only-negative case
        // (h==0, flat<d); those elements are masked to 1.0 anyway.
        const float r0 = rp[max(flat + 0 - d, 0)];
        const float r1 = rp[max(flat + 1 - d, 0)];
        const float r2 = rp[max(flat + 2 - d, 0)];
        const float r3 = rp[max(flat + 3 - d, 0)];

        float4 o;
        o.x = (x + 0 >= d) ? lv.x - r0 : 1.0f;
        o.y = (x + 1 >= d) ? lv.y - r1 : 1.0f;
        o.z = (x + 2 >= d) ? lv.z - r2 : 1.0f;
        o.w = (x + 3 >= d) ? lv.w - r3 : 1.0f;

        *reinterpret_cast<float4*>(op + flat) = o;
    }
}

extern "C" void kernel_launch(void* const* d_in, const int* in_sizes, int n_in,
                              void* d_out, int out_size, void* d_ws, size_t ws_size,
                              hipStream_t stream)
{
    const float* l = (const float*)d_in[0];
    const float* r = (const float*)d_in[1];
    float* out = (float*)d_out;

    cost_volume_kernel<<<NC * D, 256, 0, stream>>>(l, r, out);
}